// Round 6
// baseline (1193.107 us; speedup 1.0000x reference)
//
#include <hip/hip_runtime.h>

// RGCN: N=50000, E=600000, D=128, R=200, NB=4, ARD=32, L=2, G=50, NS=2000
// R5: k_attn rebuilt on MFMA with ZERO LDS. Output mapped as q^T (M=j, N=edge):
//     A-frag = pre-split AQhi/lo[j][64] bf16 tables (built in k_bigwT, L1-resident),
//     B-frag = re/tr rows converted to bf16x2 in-reg (16 floats/lane, once/wave).
//     48 MFMAs per 16 edges replace the VALU q-GEMM (was 62% VALUBusy, 1.2e7 LDS
//     conflicts). Epilogue: half4 psrc/ptgt gathers, h+dot in reg, shfl_xor(16|32),
//     sigmoid -> acf[epos[e]]. k_zero folded away (graphsum -> per-chunk partials).
//   per layer l:
//     k_bigwT  : BigW^T split (896x128) + AQ split (128x64) bf16 hi/lo
//     k_splitX : X -> Xhi/Xlo bf16x2 (NP=50048 padded)
//     k_mgemm  : 3-pass bf16x2 MFMA -> xw16 (Nx512 fp16), pst16 (Nx256 fp16),
//                curr -> feats[:, l*128:+128] fp32
//     k_attn   : MFMA q-GEMM + MLP -> acf (CSR order)
//     k_reduce : wave-per-tgt CSR reduction over fp16 xw, fp32 accum
// All accumulation fp32. ws ~169 MB.

#define NN 50000
#define NP 50048   // 391 * 128
#define EE 600000
#define DD 128
#define RR 200
#define NBASIS 4
#define LL 2
#define GG 50
#define NSRC 2000
#define GCH 8

typedef __attribute__((ext_vector_type(8))) short short8v;
typedef __attribute__((ext_vector_type(4))) float float4v;
typedef __attribute__((ext_vector_type(8))) _Float16 half8v;
typedef __attribute__((ext_vector_type(4))) _Float16 half4v;

__device__ __forceinline__ void f4a(const float4 v, float* a) {
  a[0] = v.x; a[1] = v.y; a[2] = v.z; a[3] = v.w;
}

__device__ __forceinline__ unsigned short f2bf(float v) {  // RNE bf16
  unsigned u = __float_as_uint(v);
  unsigned r = u + 0x7FFFu + ((u >> 16) & 1u);
  return (unsigned short)(r >> 16);
}
__device__ __forceinline__ float bf2f(unsigned short h) {
  return __uint_as_float(((unsigned)h) << 16);
}

// -------- BigW^T assembly + bf16x2 split; also AQ (attention A_w cols 256..319) -----
__global__ __launch_bounds__(256) void k_bigwT(const float* __restrict__ weights,
                                               const float* __restrict__ A_w,
                                               const float* __restrict__ self_loops,
                                               unsigned short* __restrict__ BThi,
                                               unsigned short* __restrict__ BTlo,
                                               unsigned short* __restrict__ AQhi,
                                               unsigned short* __restrict__ AQlo, int l) {
  int id = blockIdx.x * 256 + threadIdx.x;
  if (id >= 128 * 960) return;
  if (id < 128 * 896) {
    int i = id / 896, c = id % 896;  // i = K index, c = output col
    float v;
    if (c < 512) {            // xw: col b*128+o = weights[l][b][i][o]
      int b = c >> 7, o = c & 127;
      v = weights[((l * NBASIS + b) * DD + i) * DD + o];
    } else if (c < 640) {     // psrc
      int j = c - 512;
      v = A_w[(l * DD + j) * 320 + i];
    } else if (c < 768) {     // ptgt
      int j = c - 640;
      v = A_w[(l * DD + j) * 320 + 128 + i];
    } else {                  // curr
      int o = c - 768;
      v = self_loops[(l * DD + i) * DD + o];
    }
    unsigned short hi = f2bf(v);
    unsigned short lo = f2bf(v - bf2f(hi));
    BThi[c * 128 + i] = hi;
    BTlo[c * 128 + i] = lo;
  } else {                    // AQ[j][k] = A_w[l][j][256+k], j<128, k<64
    int idx = id - 128 * 896;
    int j = idx >> 6, k = idx & 63;
    float v = A_w[(l * DD + j) * 320 + 256 + k];
    unsigned short hi = f2bf(v);
    unsigned short lo = f2bf(v - bf2f(hi));
    AQhi[idx] = hi;
    AQlo[idx] = lo;
  }
}

// ---------------- X bf16x2 split (padded to NP rows) ----------------
__global__ __launch_bounds__(256) void k_splitX(const float* __restrict__ X, int xs,
                                                unsigned short* __restrict__ Xhi,
                                                unsigned short* __restrict__ Xlo) {
  int id = blockIdx.x * 256 + threadIdx.x;
  if (id >= NP * 128) return;
  int n = id >> 7, k = id & 127;
  float v = (n < NN) ? X[(size_t)n * xs + k] : 0.0f;
  unsigned short hi = f2bf(v);
  unsigned short lo = f2bf(v - bf2f(hi));
  Xhi[id] = hi;
  Xlo[id] = lo;
}

// ---------------- MFMA node GEMM: block 128m x 128n, wave 32m x 128n ----------------
__global__ __launch_bounds__(256) void k_mgemm(const unsigned short* __restrict__ Xhi,
                                               const unsigned short* __restrict__ Xlo,
                                               const unsigned short* __restrict__ BThi,
                                               const unsigned short* __restrict__ BTlo,
                                               _Float16* __restrict__ xw16,
                                               _Float16* __restrict__ pst16,
                                               float* __restrict__ currdst) {
  __shared__ __align__(16) char smem[34816];
  unsigned short* sBhi = (unsigned short*)smem;        // [128][56] halves
  unsigned short* sBlo = sBhi + 128 * 56;
  _Float16* sC = (_Float16*)smem;                      // [128][136] halves
  float* sCf = (float*)smem;                           // [64][132] floats

  const int t = threadIdx.x;
  const int wv = t >> 6, lane = t & 63;
  const int lm = lane & 15, qd = lane >> 4;
  const int m0 = blockIdx.x * 128;
  const int cb = blockIdx.y;           // 0..6
  const int n0 = cb * 128;
  const int mw = m0 + wv * 32;

  float4v acc[2][8];
#pragma unroll
  for (int mi = 0; mi < 2; ++mi)
#pragma unroll
    for (int nt = 0; nt < 8; ++nt) acc[mi][nt] = (float4v)(0.0f);

  const int sn = (t >> 2);
  const int skq = (t & 3) * 8;

  for (int kc = 0; kc < 128; kc += 32) {
    short8v vh0 = *(const short8v*)(BThi + (size_t)(n0 + sn) * 128 + kc + skq);
    short8v vl0 = *(const short8v*)(BTlo + (size_t)(n0 + sn) * 128 + kc + skq);
    short8v vh1 = *(const short8v*)(BThi + (size_t)(n0 + 64 + sn) * 128 + kc + skq);
    short8v vl1 = *(const short8v*)(BTlo + (size_t)(n0 + 64 + sn) * 128 + kc + skq);
    if (kc) __syncthreads();
    *(short8v*)&sBhi[sn * 56 + skq] = vh0;
    *(short8v*)&sBlo[sn * 56 + skq] = vl0;
    *(short8v*)&sBhi[(64 + sn) * 56 + skq] = vh1;
    *(short8v*)&sBlo[(64 + sn) * 56 + skq] = vl1;
    __syncthreads();
    short8v ah[2], al[2];
#pragma unroll
    for (int mi = 0; mi < 2; ++mi) {
      ah[mi] = *(const short8v*)(Xhi + (size_t)(mw + mi * 16 + lm) * 128 + kc + qd * 8);
      al[mi] = *(const short8v*)(Xlo + (size_t)(mw + mi * 16 + lm) * 128 + kc + qd * 8);
    }
#pragma unroll
    for (int nt = 0; nt < 8; ++nt) {
      short8v bh = *(const short8v*)&sBhi[(nt * 16 + lm) * 56 + qd * 8];
      short8v bl = *(const short8v*)&sBlo[(nt * 16 + lm) * 56 + qd * 8];
#pragma unroll
      for (int mi = 0; mi < 2; ++mi) {
        acc[mi][nt] = __builtin_amdgcn_mfma_f32_16x16x32_bf16(ah[mi], bh, acc[mi][nt], 0, 0, 0);
        acc[mi][nt] = __builtin_amdgcn_mfma_f32_16x16x32_bf16(ah[mi], bl, acc[mi][nt], 0, 0, 0);
        acc[mi][nt] = __builtin_amdgcn_mfma_f32_16x16x32_bf16(al[mi], bh, acc[mi][nt], 0, 0, 0);
      }
    }
  }

  // epilogue: C/D layout col = lane&15, row = qd*4 + reg  [m89/m91]
  if (cb < 6) {
    _Float16* dst16; int stride, off;
    if (cb < 4) { dst16 = xw16;  stride = 512; off = cb * 128; }
    else        { dst16 = pst16; stride = 256; off = (cb - 4) * 128; }
    __syncthreads();
#pragma unroll
    for (int mi = 0; mi < 2; ++mi)
#pragma unroll
      for (int nt = 0; nt < 8; ++nt)
#pragma unroll
        for (int r = 0; r < 4; ++r)
          sC[(wv * 32 + mi * 16 + qd * 4 + r) * 136 + nt * 16 + lm] =
              (_Float16)acc[mi][nt][r];
    __syncthreads();
#pragma unroll
    for (int rep = 0; rep < 8; ++rep) {
      int idx = rep * 256 + t;
      int row = idx >> 4, li = idx & 15;
      int m = m0 + row;
      if (m < NN)
        *(half8v*)&dst16[(size_t)m * stride + off + li * 8] =
            *(const half8v*)&sC[row * 136 + li * 8];
    }
  } else {
#pragma unroll
    for (int pass = 0; pass < 2; ++pass) {
      __syncthreads();
      if ((wv >> 1) == pass) {
        int rbase = (wv & 1) * 32;
#pragma unroll
        for (int mi = 0; mi < 2; ++mi)
#pragma unroll
          for (int nt = 0; nt < 8; ++nt)
#pragma unroll
            for (int r = 0; r < 4; ++r)
              sCf[(rbase + mi * 16 + qd * 4 + r) * 132 + nt * 16 + lm] = acc[mi][nt][r];
      }
      __syncthreads();
#pragma unroll
      for (int rep = 0; rep < 8; ++rep) {
        int idx = rep * 256 + t;
        int lr = idx >> 5, li = idx & 31;
        int m = m0 + pass * 64 + lr;
        if (m < NN)
          *(float4*)&currdst[(size_t)m * 256 + li * 4] =
              *(const float4*)&sCf[lr * 132 + li * 4];
      }
    }
  }
}

// ---------------- MFMA attention: zero LDS, 64 edges/block, q^T mapping ----------------
// Wave handles 16 edges. M = j (8 tiles of 16), N = edge (lane&15), K = 64.
// A = AQ split tables; B = re/tr rows converted to bf16x2 in-reg.
// C layout: col = edge = lane&15, row = j_local = qd*4+r  -> j = nt*16+qd*4+r.
__global__ __launch_bounds__(256) void k_attn(
    const int* __restrict__ e_src, const int* __restrict__ e_tgt,
    const int* __restrict__ rel, const int* __restrict__ epos,
    const float* __restrict__ re, const float* __restrict__ tr,
    const unsigned short* __restrict__ AQhi, const unsigned short* __restrict__ AQlo,
    const float* __restrict__ A_b, const float* __restrict__ B_w,
    const float* __restrict__ B_b, const float* __restrict__ w_comps,
    const _Float16* __restrict__ pst16, float* __restrict__ acf, int l) {
  const int t = threadIdx.x;
  const int wv = t >> 6, lane = t & 63;
  const int lm = lane & 15, qd = lane >> 4;
  const int e = blockIdx.x * 64 + wv * 16 + lm;

  // B-frags: ecat[e][k], chunk0 k=0..31 from re, chunk1 from tr; lane covers k=qd*8..+7
  float rv[16];
  f4a(*(const float4*)&re[(size_t)e * 32 + qd * 8], rv);
  f4a(*(const float4*)&re[(size_t)e * 32 + qd * 8 + 4], rv + 4);
  f4a(*(const float4*)&tr[(size_t)e * 32 + qd * 8], rv + 8);
  f4a(*(const float4*)&tr[(size_t)e * 32 + qd * 8 + 4], rv + 12);
  short8v bh[2], bl[2];
#pragma unroll
  for (int c = 0; c < 2; ++c)
#pragma unroll
    for (int j = 0; j < 8; ++j) {
      float v = rv[c * 8 + j];
      unsigned short h = f2bf(v);
      bh[c][j] = (short)h;
      bl[c][j] = (short)f2bf(v - bf2f(h));
    }

  float4v acc[8];
#pragma unroll
  for (int nt = 0; nt < 8; ++nt) acc[nt] = (float4v)(0.0f);
#pragma unroll
  for (int c = 0; c < 2; ++c) {
#pragma unroll
    for (int nt = 0; nt < 8; ++nt) {
      short8v ah = *(const short8v*)&AQhi[(nt * 16 + lm) * 64 + c * 32 + qd * 8];
      short8v al = *(const short8v*)&AQlo[(nt * 16 + lm) * 64 + c * 32 + qd * 8];
      acc[nt] = __builtin_amdgcn_mfma_f32_16x16x32_bf16(ah, bh[c], acc[nt], 0, 0, 0);
      acc[nt] = __builtin_amdgcn_mfma_f32_16x16x32_bf16(ah, bl[c], acc[nt], 0, 0, 0);
      acc[nt] = __builtin_amdgcn_mfma_f32_16x16x32_bf16(al, bh[c], acc[nt], 0, 0, 0);
    }
  }

  // epilogue: h = relu(q + psrc + ptgt + Ab), part = sum_j h*Bw
  const int src = e_src[e], tgt = e_tgt[e];
  float part = 0.0f;
#pragma unroll
  for (int nt = 0; nt < 8; ++nt) {
    const int jb = nt * 16 + qd * 4;
    half4v ps = *(const half4v*)&pst16[(size_t)src * 256 + jb];
    half4v pt = *(const half4v*)&pst16[(size_t)tgt * 256 + 128 + jb];
    float ab[4], bw[4];
    f4a(*(const float4*)&A_b[l * DD + jb], ab);
    f4a(*(const float4*)&B_w[l * DD + jb], bw);
#pragma unroll
    for (int r = 0; r < 4; ++r) {
      float pre = acc[nt][r] + (float)ps[r] + (float)pt[r] + ab[r];
      part += fmaxf(pre, 0.0f) * bw[r];
    }
  }
  part += __shfl_xor(part, 16, 64);
  part += __shfl_xor(part, 32, 64);
  if (lane < 16) {
    const float a = 1.0f / (1.0f + expf(-(part + B_b[l])));
    const float4 cf = *(const float4*)&w_comps[(l * RR + rel[e]) * 4];
    const int p = epos[e];
    *(float4*)&acf[(size_t)p * 4] = make_float4(a * cf.x, a * cf.y, a * cf.z, a * cf.w);
  }
}

// ---------------- CSR build ----------------
__global__ __launch_bounds__(256) void k_zero_i(int* __restrict__ p, int n) {
  int id = blockIdx.x * 256 + threadIdx.x;
  if (id < n) p[id] = 0;
}
__global__ __launch_bounds__(256) void k_hist(const int* __restrict__ e_tgt,
                                              int* __restrict__ deg) {
  int e = blockIdx.x * 256 + threadIdx.x;
  if (e < EE) atomicAdd(&deg[e_tgt[e]], 1);
}
__global__ __launch_bounds__(1024) void k_scan(const int* __restrict__ deg,
                                               int* __restrict__ rowptr,
                                               int* __restrict__ cursor) {
  __shared__ int part[1024];
  const int t = threadIdx.x;
  const int chunk = (NN + 1023) / 1024;  // 49
  int lo = t * chunk, hi = min(lo + chunk, NN);
  int s = 0;
  for (int i = lo; i < hi; ++i) s += deg[i];
  part[t] = s;
  __syncthreads();
  for (int off = 1; off < 1024; off <<= 1) {
    int v = (t >= off) ? part[t - off] : 0;
    __syncthreads();
    part[t] += v;
    __syncthreads();
  }
  int run = (t == 0) ? 0 : part[t - 1];
  for (int i = lo; i < hi; ++i) {
    int d = deg[i];
    rowptr[i] = run; cursor[i] = run;
    run += d;
  }
  if (t == 0) rowptr[NN] = EE;
}
__global__ __launch_bounds__(256) void k_fill(const int* __restrict__ e_tgt,
                                              const int* __restrict__ e_src,
                                              int* __restrict__ cursor,
                                              int* __restrict__ srcs,
                                              int* __restrict__ epos) {
  int e = blockIdx.x * 256 + threadIdx.x;
  if (e < EE) {
    int p = atomicAdd(&cursor[e_tgt[e]], 1);
    srcs[p] = e_src[e];
    epos[e] = p;
  }
}

// ---------------- CSR segmented reduction: one wave per tgt node ----------------
__global__ __launch_bounds__(256) void k_reduce(
    const int* __restrict__ rowptr, const int* __restrict__ srcs,
    const float* __restrict__ acf, const _Float16* __restrict__ xw16,
    float* __restrict__ feats, int l) {
  const int t = threadIdx.x;
  const int wave = t >> 6, lane = t & 63;
  const int n = blockIdx.x * 4 + wave;
  if (n >= NN) return;
  const int b = lane >> 4, li = lane & 15;
  float s[8] = {0, 0, 0, 0, 0, 0, 0, 0};
  const int lo = rowptr[n], hi = rowptr[n + 1];
  int snext = 0; float cnext = 0.0f;
  if (lo < hi) { snext = srcs[lo]; cnext = acf[lo * 4 + b]; }
  for (int i = lo; i < hi; ++i) {
    const int src = snext; const float cb_ = cnext;
    if (i + 1 < hi) { snext = srcs[i + 1]; cnext = acf[(i + 1) * 4 + b]; }
    half8v x = *(const half8v*)&xw16[(size_t)src * 512 + b * 128 + li * 8];
#pragma unroll
    for (int j = 0; j < 8; ++j) s[j] += cb_ * (float)x[j];
  }
#pragma unroll
  for (int j = 0; j < 8; ++j) {
    s[j] += __shfl_xor(s[j], 16, 64);
    s[j] += __shfl_xor(s[j], 32, 64);
  }
  if (lane < 16) {
    float* fp = &feats[(size_t)n * 256 + l * 128 + lane * 8];
    float4 c0 = *(const float4*)fp;
    float4 c1 = *(const float4*)(fp + 4);
    float4 o0 = make_float4(fmaxf(s[0] + c0.x, 0.f), fmaxf(s[1] + c0.y, 0.f),
                            fmaxf(s[2] + c0.z, 0.f), fmaxf(s[3] + c0.w, 0.f));
    float4 o1 = make_float4(fmaxf(s[4] + c1.x, 0.f), fmaxf(s[5] + c1.y, 0.f),
                            fmaxf(s[6] + c1.z, 0.f), fmaxf(s[7] + c1.w, 0.f));
    *(float4*)fp = o0;
    *(float4*)(fp + 4) = o1;
  }
}

// ---------------- readout ----------------
__global__ __launch_bounds__(256) void k_gather(const int* __restrict__ srcn,
                                                const int* __restrict__ tgtn,
                                                const float* __restrict__ feats,
                                                float* __restrict__ out) {
  int id = blockIdx.x * 256 + threadIdx.x;
  if (id >= 2 * NSRC * 256) return;
  int half = id / (NSRC * 256);
  int rem = id % (NSRC * 256);
  int s = rem >> 8, c = rem & 255;
  int n = half ? tgtn[s] : srcn[s];
  int base = GG * 256 + half * NSRC * 256;
  out[base + s * 256 + c] = feats[n * 256 + c];
}

// graph mean: block = (g, chunk); non-atomic partials into gpart
__global__ __launch_bounds__(256) void k_graphsum(const int* __restrict__ gid,
                                                  const float* __restrict__ feats,
                                                  float* __restrict__ gpart,
                                                  float* __restrict__ gcnt) {
  const int g = blockIdx.x / GCH, ch = blockIdx.x % GCH;
  __shared__ int sb[2];
  if (threadIdx.x == 0) {
    int lo = 0, hi = NN;
    while (lo < hi) { int m = (lo + hi) >> 1; if (gid[m] < g) lo = m + 1; else hi = m; }
    sb[0] = lo;
    lo = 0; hi = NN;
    while (lo < hi) { int m = (lo + hi) >> 1; if (gid[m] < g + 1) lo = m + 1; else hi = m; }
    sb[1] = lo;
  }
  __syncthreads();
  const int lo = sb[0], hi = sb[1];
  if (ch == 0 && threadIdx.x == 0) gcnt[g] = (float)(hi - lo);
  const int cnt = hi - lo;
  const int per = (cnt + GCH - 1) / GCH;
  const int nlo = lo + ch * per, nhi = min(nlo + per, hi);
  float s = 0.0f;
  const int c = threadIdx.x;
  for (int n = nlo; n < nhi; ++n) s += feats[n * 256 + c];
  gpart[(size_t)(g * GCH + ch) * 256 + c] = s;
}

__global__ __launch_bounds__(256) void k_graphdiv(const float* __restrict__ gpart,
                                                  const float* __restrict__ gcnt,
                                                  float* __restrict__ out) {
  int id = blockIdx.x * 256 + threadIdx.x;
  if (id >= GG * 256) return;
  int g = id >> 8, c = id & 255;
  float s = 0.0f;
#pragma unroll
  for (int ch = 0; ch < GCH; ++ch) s += gpart[(size_t)(g * GCH + ch) * 256 + c];
  out[id] = s / gcnt[g];
}

extern "C" void kernel_launch(void* const* d_in, const int* in_sizes, int n_in,
                              void* d_out, int out_size, void* d_ws, size_t ws_size,
                              hipStream_t stream) {
  const float* node_feat  = (const float*)d_in[0];
  const int*   edge       = (const int*)d_in[1];
  const int*   rel        = (const int*)d_in[2];
  const float* re         = (const float*)d_in[3];
  const float* tr         = (const float*)d_in[4];
  const int*   srcn       = (const int*)d_in[5];
  const int*   tgtn       = (const int*)d_in[6];
  const int*   gid        = (const int*)d_in[7];
  const float* weights    = (const float*)d_in[8];
  const float* w_comps    = (const float*)d_in[9];
  const float* self_loops = (const float*)d_in[10];
  const float* A_w        = (const float*)d_in[11];
  const float* A_b        = (const float*)d_in[12];
  const float* B_w        = (const float*)d_in[13];
  const float* B_b        = (const float*)d_in[14];
  float* out = (float*)d_out;

  float* ws    = (float*)d_ws;
  float* feats = ws;                            // N*256 f32
  float* gpart = feats + (size_t)NN * 256;      // GG*GCH*256
  float* gcnt  = gpart + GG * GCH * 256;        // 64
  float* acf   = gcnt + 64;                     // E*4
  _Float16* xw16  = (_Float16*)(acf + (size_t)EE * 4);  // N*512 fp16
  _Float16* pst16 = xw16 + (size_t)NN * 512;            // N*256 fp16
  unsigned short* Xhi  = (unsigned short*)(pst16 + (size_t)NN * 256);  // NP*128
  unsigned short* Xlo  = Xhi + (size_t)NP * 128;
  unsigned short* BThi = Xlo + (size_t)NP * 128;        // 896*128
  unsigned short* BTlo = BThi + 896 * 128;
  unsigned short* AQhi = BTlo + 896 * 128;              // 128*64
  unsigned short* AQlo = AQhi + 128 * 64;
  int* deg    = (int*)(AQlo + 128 * 64);        // N
  int* rowptr = deg + NN;                       // N+1
  int* cursor = rowptr + NN + 1;                // N
  int* srcs   = cursor + NN;                    // E
  int* epos   = srcs + EE;                      // E
  // total ws ~170 MB

  const int* e_src = edge;
  const int* e_tgt = edge + EE;

  // CSR by tgt (layer-invariant)
  k_zero_i<<<(NN + 255) / 256, 256, 0, stream>>>(deg, NN);
  k_hist<<<(EE + 255) / 256, 256, 0, stream>>>(e_tgt, deg);
  k_scan<<<1, 1024, 0, stream>>>(deg, rowptr, cursor);
  k_fill<<<(EE + 255) / 256, 256, 0, stream>>>(e_tgt, e_src, cursor, srcs, epos);

  for (int l = 0; l < LL; ++l) {
    const float* X = (l == 0) ? node_feat : feats;  // layer1 input = feats[:, 0:128]
    int xs = (l == 0) ? 128 : 256;
    k_bigwT<<<(128 * 960 + 255) / 256, 256, 0, stream>>>(weights, A_w, self_loops,
                                                         BThi, BTlo, AQhi, AQlo, l);
    k_splitX<<<(NP * 128 + 255) / 256, 256, 0, stream>>>(X, xs, Xhi, Xlo);
    dim3 g1(NP / 128, 7);
    k_mgemm<<<g1, 256, 0, stream>>>(Xhi, Xlo, BThi, BTlo, xw16, pst16, feats + l * 128);
    k_attn<<<EE / 64, 256, 0, stream>>>(e_src, e_tgt, rel, epos, re, tr, AQhi, AQlo,
                                        A_b, B_w, B_b, w_comps, pst16, acf, l);
    k_reduce<<<(NN + 3) / 4, 256, 0, stream>>>(rowptr, srcs, acf, xw16, feats, l);
  }
  k_gather<<<(2 * NSRC * 256 + 255) / 256, 256, 0, stream>>>(srcn, tgtn, feats, out);
  k_graphsum<<<GG * GCH, 256, 0, stream>>>(gid, feats, gpart, gcnt);
  k_graphdiv<<<GG, 256, 0, stream>>>(gpart, gcnt, out);
}